// Round 13
// baseline (29.119 us; speedup 1.0000x reference)
//
#include <hip/hip_runtime.h>

constexpr int NQ = 7;
constexpr int NL = 4;
constexpr int NG = NL * NQ;   // 28
constexpr int NCLS = 22;
constexpr int EPB = 32;       // elements per 1024-thread block (one per 32-lane half)

// ---------------- cross-lane primitives (all HW-proven) ----------------
// masks 1,2 -> DPP quad_perm (R1..R12); mask 8 -> DPP ROW_ROR:8 (R12-proven);
// masks 4,16 -> ds_swizzle XOR (R1..R12); gather -> __shfl (R1/R11/R12-proven).
template<int CTRL>
__device__ __forceinline__ float fdpp(float v) {
    return __int_as_float(__builtin_amdgcn_mov_dpp(__float_as_int(v), CTRL, 0xF, 0xF, true));
}
template<int OFF>
__device__ __forceinline__ float fswz(float v) {
    return __int_as_float(__builtin_amdgcn_ds_swizzle(__float_as_int(v), OFF));
}
template<int M>
__device__ __forceinline__ float xorl(float v) {
    if      constexpr (M == 1)  return fdpp<0xB1>(v);    // quad_perm [1,0,3,2]
    else if constexpr (M == 2)  return fdpp<0x4E>(v);    // quad_perm [2,3,0,1]
    else if constexpr (M == 4)  return fswz<0x101F>(v);  // xor4
    else if constexpr (M == 8)  return fdpp<0x128>(v);   // ROW_ROR:8 == xor8 (R12-proven)
    else                        return fswz<0x401F>(v);  // xor16
}

// ---------------- fused gate build: U' = U_rot @ RX(c,s) ----------------
__device__ __forceinline__ void fuse(const float* __restrict__ u, float c, float s,
                                     float4& A, float4& B) {
    A.x = fmaf(c, u[0],  s * u[3]);  A.y = fmaf(c, u[1], -s * u[2]);
    A.z = fmaf(c, u[2],  s * u[1]);  A.w = fmaf(c, u[3], -s * u[0]);
    B.x = fmaf(c, u[4],  s * u[7]);  B.y = fmaf(c, u[5], -s * u[6]);
    B.z = fmaf(c, u[6],  s * u[5]);  B.w = fmaf(c, u[7], -s * u[4]);
}

// 2x2 gate on a lane-bit qubit: batch-fetch partners, then FMAs (4 amps)
template<int M>
__device__ __forceinline__ void gateL(int lane, float4 A, float4 B,
                                      float ar[4], float ai[4]) {
    const bool hi = (lane & M) != 0;
    const float avr = hi ? B.z : A.x, avi = hi ? B.w : A.y;   // diag coeff
    const float awr = hi ? B.x : A.z, awi = hi ? B.y : A.w;   // off-diag coeff
    float wr[4], wi[4];
    #pragma unroll
    for (int k = 0; k < 4; ++k) { wr[k] = xorl<M>(ar[k]); wi[k] = xorl<M>(ai[k]); }
    #pragma unroll
    for (int k = 0; k < 4; ++k) {
        const float nr = avr*ar[k] - avi*ai[k] + awr*wr[k] - awi*wi[k];
        const float ni = avr*ai[k] + avi*ar[k] + awr*wi[k] + awi*wr[k];
        ar[k] = nr; ai[k] = ni;
    }
}

// full 2x2 on a register pair (v = row0 amp, w = row1 amp)
__device__ __forceinline__ void gate2(float4 A, float4 B,
                                      float& vr, float& vi, float& wr, float& wi) {
    const float n0r = A.x*vr - A.y*vi + A.z*wr - A.w*wi;
    const float n0i = A.x*vi + A.y*vr + A.z*wi + A.w*wr;
    const float n1r = B.x*vr - B.y*vi + B.z*wr - B.w*wi;
    const float n1i = B.x*vi + B.y*vr + B.z*wi + B.w*wr;
    vr = n0r; vi = n0i; wr = n1r; wi = n1i;
}

// ---------------- main kernel: 1024-thread blocks, TWO elements/wave ----------------
// element = 32-lane half: grp = tid>>5 (0..31); within-half lane wl = lane&31.
// amp index a = (wl<<2)|k, bits a6..a0 = w4 w3 w2 w1 w0 k1 k0.
// qubit q <-> amp bit (6-q): q0->w4(m16) q1->w3(m8) q2->w2(m4) q3->w1(m2)
//                            q4->w0(m1)  q5->k1(local) q6->k0(local)
__global__ __launch_bounds__(1024, 8) void reupload_kernel(
    const float* __restrict__ x,       // (B,7)
    const float* __restrict__ wts,     // (4,7,3)
    const float* __restrict__ fc1_w,   // (32,7)
    const float* __restrict__ fc1_b,   // (32,)
    const float* __restrict__ fc2_w,   // (22,32)
    const float* __restrict__ fc2_b,   // (22,)
    float* __restrict__ out,           // (B,22)
    int B)
{
    __shared__ __align__(16) float rotU[NG * 8];        // 28 Rot matrices (896 B)
    __shared__ float2 csb[EPB * NQ];                    // per-element RX (1.8 KB)
    __shared__ __align__(16) float fU[NG * EPB * 8];    // fused matrices (28.7 KB)
    __shared__ __align__(16) float hbuf[EPB][32];       // MLP hidden (4 KB)

    const int tid = threadIdx.x;
    // --- phase 0: c,s (224 thr, waves 0-3) ∥ Rot matrices (28 thr, wave 4) ---
    if (tid < EPB * NQ) {
        const int e = tid / NQ, q = tid % NQ;
        const int bb = blockIdx.x * EPB + e;
        const float xv = (bb < B) ? x[bb*NQ + q] : 0.f;
        const float h = 0.5f * xv;
        csb[tid] = make_float2(__cosf(h), __sinf(h));
    } else if (tid >= 256 && tid < 256 + NG) {
        const int g = tid - 256;
        float phi = wts[g*3+0], th = wts[g*3+1], om = wts[g*3+2];
        float ct = __cosf(0.5f*th), st = __sinf(0.5f*th);
        float ap = 0.5f*(phi+om),  am = 0.5f*(phi-om);
        float cp = __cosf(ap), sp = __sinf(ap);
        float cm = __cosf(am), sm = __sinf(am);
        float* u = &rotU[g*8];
        u[0] =  cp*ct; u[1] = -sp*ct;   // u00 = ep*ct        (ep = cp - i sp)
        u[2] = -cm*st; u[3] = -sm*st;   // u01 = -conj(em)*st (em = cm - i sm)
        u[4] =  cm*st; u[5] = -sm*st;   // u10 = em*st
        u[6] =  cp*ct; u[7] =  sp*ct;   // u11 = conj(ep)*ct
    }
    __syncthreads();
    // --- phase 1: build fused matrices (896 jobs, 1 per thread) ---
    if (tid < NG * EPB) {
        const int g = tid >> 5, e = tid & 31;
        const int q = g % NQ;
        const float2 cs = csb[e*NQ + q];
        float4 A, Bq;
        fuse(&rotU[g*8], cs.x, cs.y, A, Bq);
        float4* dst = reinterpret_cast<float4*>(&fU[(g*EPB + e)*8]);
        dst[0] = A; dst[1] = Bq;
    }
    __syncthreads();

    const int lane = threadIdx.x & 63;
    const int wl   = threadIdx.x & 31;          // within-half lane
    const int grp  = threadIdx.x >> 5;          // element slot in block (0..31)
    const int b    = blockIdx.x * EPB + grp;
    if (b >= B) return;

    // merged CNOT(0,1)(1,2)(2,3)(3,4) gather: src_w = w ^ (w>>1) (5 bits)
    const int srcLane = (lane & 32) | ((wl ^ (wl >> 1)) & 31);

    // |0..0>: amp 0 at wl=0,k=0
    float ar[4], ai[4];
    #pragma unroll
    for (int k = 0; k < 4; ++k) { ar[k] = 0.f; ai[k] = 0.f; }
    ar[0] = (wl == 0) ? 1.f : 0.f;

    #pragma unroll
    for (int l = 0; l < NL; ++l) {
        float4 A, Bq;
        #define LOADU(q) { const float4* up = reinterpret_cast<const float4*>( \
            &fU[((l*NQ + (q))*EPB + grp)*8]); A = up[0]; Bq = up[1]; }
        LOADU(0); gateL<16>(lane, A, Bq, ar, ai);   // q0 -> w4 (swz)
        LOADU(1); gateL< 8>(lane, A, Bq, ar, ai);   // q1 -> w3 (DPP)
        LOADU(2); gateL< 4>(lane, A, Bq, ar, ai);   // q2 -> w2 (swz)
        LOADU(3); gateL< 2>(lane, A, Bq, ar, ai);   // q3 -> w1 (DPP)
        LOADU(4); gateL< 1>(lane, A, Bq, ar, ai);   // q4 -> w0 (DPP)
        LOADU(5);                                   // q5 -> k1: pairs (0,2),(1,3)
        gate2(A, Bq, ar[0], ai[0], ar[2], ai[2]);
        gate2(A, Bq, ar[1], ai[1], ar[3], ai[3]);
        LOADU(6);                                   // q6 -> k0: pairs (0,1),(2,3)
        gate2(A, Bq, ar[0], ai[0], ar[1], ai[1]);
        gate2(A, Bq, ar[2], ai[2], ar[3], ai[3]);
        #undef LOADU

        // --- CNOT ring CNOT(q, q+1 mod 7), reference order q=0..6 ---
        // (0,1)+(1,2)+(2,3)+(3,4) merged: new[w] = old[w ^ (w>>1)] — one gather
        #pragma unroll
        for (int k = 0; k < 4; ++k) {
            ar[k] = __shfl(ar[k], srcLane);
            ai[k] = __shfl(ai[k], srcLane);
        }
        {   // (4,5): ctrl w0 (lane&1), tgt k1 -> cond swap (0<->2),(1<->3)
            const bool cc = (lane & 1) != 0;
            float t;
            t = ar[0]; ar[0] = cc ? ar[2] : ar[0]; ar[2] = cc ? t : ar[2];
            t = ai[0]; ai[0] = cc ? ai[2] : ai[0]; ai[2] = cc ? t : ai[2];
            t = ar[1]; ar[1] = cc ? ar[3] : ar[1]; ar[3] = cc ? t : ar[3];
            t = ai[1]; ai[1] = cc ? ai[3] : ai[1]; ai[3] = cc ? t : ai[3];
        }
        {   // (5,6): ctrl k1, tgt k0 -> unconditional 2<->3 (free reg rename)
            float t;
            t = ar[2]; ar[2] = ar[3]; ar[3] = t;
            t = ai[2]; ai[2] = ai[3]; ai[3] = t;
        }
        {   // (6,0): ctrl k0, tgt w4 -> odd regs swap across mask16 (uncond)
            ar[1] = xorl<16>(ar[1]); ai[1] = xorl<16>(ai[1]);
            ar[3] = xorl<16>(ar[3]); ai[3] = xorl<16>(ai[3]);
        }
    }

    // ---------- <Z_j> ----------
    float p[4];
    #pragma unroll
    for (int k = 0; k < 4; ++k) p[k] = ar[k]*ar[k] + ai[k]*ai[k];
    const float t01 = p[0] + p[1], t23 = p[2] + p[3];
    const float t = t01 + t23;
    float z[NQ];
    z[0] = (lane & 16) ? -t : t;
    z[1] = (lane &  8) ? -t : t;
    z[2] = (lane &  4) ? -t : t;
    z[3] = (lane &  2) ? -t : t;
    z[4] = (lane &  1) ? -t : t;
    z[5] = t01 - t23;                         // sign by k1
    z[6] = (p[0] - p[1]) + (p[2] - p[3]);     // sign by k0
    // 32-lane reduction: 2 DPP xor stages -> quad-uniform; ror4/8/12 trick for
    // the 16-row sum (R12-proven, direction-immune); xor16 swizzle for the half.
    #pragma unroll
    for (int j = 0; j < NQ; ++j) {
        float v = z[j];
        v += xorl<1>(v);
        v += xorl<2>(v);
        const float q4  = fdpp<0x124>(v);
        const float q8  = fdpp<0x128>(v);
        const float q12 = fdpp<0x12C>(v);
        v = (v + q8) + (q4 + q12);
        v += fswz<0x401F>(v);
        z[j] = v;   // per-element sum in every lane of the half
    }

    // ---------- MLP 7 -> 32(relu) -> 22, per 32-lane half ----------
    float acc1 = fc1_b[wl];
    #pragma unroll
    for (int j = 0; j < NQ; ++j) acc1 = fmaf(z[j], fc1_w[wl*NQ + j], acc1);
    hbuf[grp][wl] = fmaxf(acc1, 0.f);
    __builtin_amdgcn_wave_barrier();
    asm volatile("s_waitcnt lgkmcnt(0)" ::: "memory");
    __builtin_amdgcn_sched_barrier(0);

    float hv[32];
    #pragma unroll
    for (int i = 0; i < 8; ++i) {   // broadcast reads within each half
        float4 v4 = *reinterpret_cast<const float4*>(&hbuf[grp][i*4]);
        hv[i*4+0] = v4.x; hv[i*4+1] = v4.y; hv[i*4+2] = v4.z; hv[i*4+3] = v4.w;
    }
    const int k = (wl < NCLS) ? wl : 0;
    float acc2 = fc2_b[k];
    const float4* w4 = reinterpret_cast<const float4*>(fc2_w + k*32);
    #pragma unroll
    for (int i = 0; i < 8; ++i) {
        float4 wv = w4[i];
        acc2 = fmaf(hv[i*4+0], wv.x, acc2);
        acc2 = fmaf(hv[i*4+1], wv.y, acc2);
        acc2 = fmaf(hv[i*4+2], wv.z, acc2);
        acc2 = fmaf(hv[i*4+3], wv.w, acc2);
    }
    if (wl < NCLS) out[b*NCLS + wl] = acc2;
}

extern "C" void kernel_launch(void* const* d_in, const int* in_sizes, int n_in,
                              void* d_out, int out_size, void* d_ws, size_t ws_size,
                              hipStream_t stream) {
    const float* x     = (const float*)d_in[0];
    const float* wts   = (const float*)d_in[1];
    const float* fc1_w = (const float*)d_in[2];
    const float* fc1_b = (const float*)d_in[3];
    const float* fc2_w = (const float*)d_in[4];
    const float* fc2_b = (const float*)d_in[5];
    float* out = (float*)d_out;

    const int B = in_sizes[0] / NQ;            // 16384
    const int grid = (B + EPB - 1) / EPB;      // 512 blocks of 1024 threads
    reupload_kernel<<<grid, 1024, 0, stream>>>(x, wts, fc1_w, fc1_b, fc2_w, fc2_b, out, B);
}

// Round 14
// 20.124 us; speedup vs baseline: 1.4469x; 1.4469x over previous
//
#include <hip/hip_runtime.h>

constexpr int NQ = 7;
constexpr int NL = 4;
constexpr int NG = NL * NQ;   // 28
constexpr int NCLS = 22;
constexpr int EPB = 16;       // elements per 256-thread block (one per 16-lane group)

typedef float v2 __attribute__((ext_vector_type(2)));
#define FMA2(a,b,c) __builtin_elementwise_fma((a),(b),(c))

__device__ __forceinline__ v2 sp(float s) { v2 r; r.x = s; r.y = s; return r; }
__device__ __forceinline__ v2 sel(bool c, v2 a, v2 b) {
    v2 r; r.x = c ? a.x : b.x; r.y = c ? a.y : b.y; return r;
}

// ---------------- cross-lane primitives (all HW-proven R1..R13) ----------------
template<int CTRL>
__device__ __forceinline__ float fdpp(float v) {
    return __int_as_float(__builtin_amdgcn_mov_dpp(__float_as_int(v), CTRL, 0xF, 0xF, true));
}
template<int OFF>
__device__ __forceinline__ float fswz(float v) {
    return __int_as_float(__builtin_amdgcn_ds_swizzle(__float_as_int(v), OFF));
}
template<int M>
__device__ __forceinline__ float xorl(float v) {
    if      constexpr (M == 1)  return fdpp<0xB1>(v);    // quad_perm [1,0,3,2]
    else if constexpr (M == 2)  return fdpp<0x4E>(v);    // quad_perm [2,3,0,1]
    else if constexpr (M == 4)  return fswz<0x101F>(v);  // xor4
    else                        return fdpp<0x128>(v);   // ROW_ROR:8 == xor8 (R12-proven)
}
template<int M>
__device__ __forceinline__ v2 shufv(v2 v) {
    v2 r; r.x = xorl<M>(v.x); r.y = xorl<M>(v.y); return r;
}

// ---------------- fused gate build: U' = U_rot @ RX(c,s) ----------------
__device__ __forceinline__ void fuse(const float* __restrict__ u, float c, float s,
                                     float4& A, float4& B) {
    A.x = fmaf(c, u[0],  s * u[3]);  A.y = fmaf(c, u[1], -s * u[2]);
    A.z = fmaf(c, u[2],  s * u[1]);  A.w = fmaf(c, u[3], -s * u[0]);
    B.x = fmaf(c, u[4],  s * u[7]);  B.y = fmaf(c, u[5], -s * u[6]);
    B.z = fmaf(c, u[6],  s * u[5]);  B.w = fmaf(c, u[7], -s * u[4]);
}

// lane-bit gate (mask M): packed state, scalar coefficient broadcast
template<int M>
__device__ __forceinline__ void gateLane(int lane, float4 A, float4 B,
                                         v2 X[4], v2 Y[4]) {
    const bool hi = (lane & M) != 0;
    const float cvr = hi ? B.z : A.x, cvi = hi ? B.w : A.y;   // diag
    const float cwr = hi ? B.x : A.z, cwi = hi ? B.y : A.w;   // off-diag
    v2 Xs[4], Ys[4];
    #pragma unroll
    for (int j = 0; j < 4; ++j) { Xs[j] = shufv<M>(X[j]); Ys[j] = shufv<M>(Y[j]); }
    #pragma unroll
    for (int j = 0; j < 4; ++j) {
        v2 nX = FMA2(sp(cvr), X[j], FMA2(sp(-cvi), Y[j], FMA2(sp(cwr), Xs[j], sp(-cwi)*Ys[j])));
        v2 nY = FMA2(sp(cvr), Y[j], FMA2(sp( cvi), X[j], FMA2(sp(cwr), Ys[j], sp( cwi)*Xs[j])));
        X[j] = nX; Y[j] = nY;
    }
}

// cross-register gate: reg ja = row-A role, reg jb = row-B role
__device__ __forceinline__ void gateCross(float4 A, float4 B,
                                          v2& Xa, v2& Ya, v2& Xb, v2& Yb) {
    v2 nXa = FMA2(sp(A.x), Xa, FMA2(sp(-A.y), Ya, FMA2(sp(A.z), Xb, sp(-A.w)*Yb)));
    v2 nYa = FMA2(sp(A.x), Ya, FMA2(sp( A.y), Xa, FMA2(sp(A.z), Yb, sp( A.w)*Xb)));
    v2 nXb = FMA2(sp(B.x), Xa, FMA2(sp(-B.y), Ya, FMA2(sp(B.z), Xb, sp(-B.w)*Yb)));
    v2 nYb = FMA2(sp(B.x), Ya, FMA2(sp( B.y), Xa, FMA2(sp(B.z), Yb, sp( B.w)*Xb)));
    Xa = nXa; Ya = nYa; Xb = nXb; Yb = nYb;
}

// ---------------- main kernel: FOUR elements per wave, packed re/im ----------------
// element = 16-lane group; in-group lane u = lane&15.
// amp a6..a0 = u3 u2 u1 u0 k2 k1 k0. Register j = (k2<<1)|k0, component = k1.
//   X[j] = (re[amp(k1=0)], re[amp(k1=1)]),  Y[j] = imag pair.
// qubit q0->u3(m8) q1->u2(m4) q2->u1(m2) q3->u0(m1) q4->k2 q5->k1(comp) q6->k0
__global__ __launch_bounds__(256) void reupload_kernel(
    const float* __restrict__ x,       // (B,7)
    const float* __restrict__ wts,     // (4,7,3)
    const float* __restrict__ fc1_w,   // (32,7)
    const float* __restrict__ fc1_b,   // (32,)
    const float* __restrict__ fc2_w,   // (22,32)
    const float* __restrict__ fc2_b,   // (22,)
    float* __restrict__ out,           // (B,22)
    int B)
{
    __shared__ __align__(16) float rotU[NG * 8];        // 28 Rot matrices
    __shared__ float2 csb[EPB * NQ];                    // per-element RX (c,s)
    __shared__ __align__(16) float fU[NG * EPB * 8];    // fused matrices (14 KB)
    __shared__ __align__(16) float fUT[NL * EPB * 8];   // q5 transposed coefs (2 KB)
    __shared__ __align__(16) float hbuf[EPB][32];

    const int tid = threadIdx.x;
    // --- phase 0: c,s (112 thr) ∥ Rot matrices (28 thr on wave 2) ---
    if (tid < EPB * NQ) {
        const int e = tid / NQ, q = tid % NQ;
        const int bb = blockIdx.x * EPB + e;
        const float xv = (bb < B) ? x[bb*NQ + q] : 0.f;
        const float h = 0.5f * xv;
        csb[tid] = make_float2(__cosf(h), __sinf(h));
    } else if (tid >= 128 && tid < 128 + NG) {
        const int g = tid - 128;
        float phi = wts[g*3+0], th = wts[g*3+1], om = wts[g*3+2];
        float ct = __cosf(0.5f*th), st = __sinf(0.5f*th);
        float ap = 0.5f*(phi+om),  am = 0.5f*(phi-om);
        float cp = __cosf(ap), sp_ = __sinf(ap);
        float cm = __cosf(am), sm = __sinf(am);
        float* u = &rotU[g*8];
        u[0] =  cp*ct; u[1] = -sp_*ct;  // u00 = ep*ct        (ep = cp - i sp)
        u[2] = -cm*st; u[3] = -sm*st;   // u01 = -conj(em)*st (em = cm - i sm)
        u[4] =  cm*st; u[5] = -sm*st;   // u10 = em*st
        u[6] =  cp*ct; u[7] =  sp_*ct;  // u11 = conj(ep)*ct
    }
    __syncthreads();
    // --- phase 1: build fused matrices (448 = 2 per thread); q5 also transposed ---
    #pragma unroll
    for (int i = tid; i < NG * EPB; i += 256) {
        const int g = i >> 4, e = i & 15;
        const int q = g % NQ;
        const float2 cs = csb[e*NQ + q];
        float4 A, Bq;
        fuse(&rotU[g*8], cs.x, cs.y, A, Bq);
        float4* dst = reinterpret_cast<float4*>(&fU[(g*EPB + e)*8]);
        dst[0] = A; dst[1] = Bq;
        if (q == 5) {   // {(u00r,u10r),(u00i,u10i),(u01r,u11r),(u01i,u11i)}
            const int l = g / NQ;
            float* td = &fUT[(l*EPB + e)*8];
            td[0] = A.x; td[1] = Bq.x; td[2] = A.y; td[3] = Bq.y;
            td[4] = A.z; td[5] = Bq.z; td[6] = A.w; td[7] = Bq.w;
        }
    }
    __syncthreads();

    const int lane = threadIdx.x & 63;
    const int u    = threadIdx.x & 15;          // in-group lane
    const int grp  = threadIdx.x >> 4;          // element slot in block (0..15)
    const int b    = blockIdx.x * EPB + grp;
    if (b >= B) return;

    // merged CNOT(0,1)(1,2)(2,3) gather source: src_u = u ^ (u>>1) (R11-proven)
    const int srcLane = (lane & 48) | ((u ^ (u >> 1)) & 15);

    // |0..0>: amp 0 -> reg 0 comp .x at u==0
    v2 X[4], Y[4];
    #pragma unroll
    for (int j = 0; j < 4; ++j) { X[j] = sp(0.f); Y[j] = sp(0.f); }
    X[0].x = (u == 0) ? 1.f : 0.f;

    #pragma unroll
    for (int l = 0; l < NL; ++l) {
        float4 A, Bq;
        #define LOADU(q) { const float4* up = reinterpret_cast<const float4*>( \
            &fU[((l*NQ + (q))*EPB + grp)*8]); A = up[0]; Bq = up[1]; }
        LOADU(0); gateLane<8>(lane, A, Bq, X, Y);   // q0 -> u3
        LOADU(1); gateLane<4>(lane, A, Bq, X, Y);   // q1 -> u2
        LOADU(2); gateLane<2>(lane, A, Bq, X, Y);   // q2 -> u1
        LOADU(3); gateLane<1>(lane, A, Bq, X, Y);   // q3 -> u0
        LOADU(4);                                   // q4 -> k2: reg pairs (0,2),(1,3)
        gateCross(A, Bq, X[0], Y[0], X[2], Y[2]);
        gateCross(A, Bq, X[1], Y[1], X[3], Y[3]);
        {   // q5 -> k1: within-register, paired coefficients
            const v2* tp = reinterpret_cast<const v2*>(&fUT[(l*EPB + grp)*8]);
            const v2 c00r = tp[0], c00i = tp[1], c01r = tp[2], c01i = tp[3];
            #pragma unroll
            for (int j = 0; j < 4; ++j) {
                const v2 Xxx = X[j].xx, Xyy = X[j].yy;
                const v2 Yxx = Y[j].xx, Yyy = Y[j].yy;
                v2 nX = FMA2(c00r, Xxx, FMA2(-c00i, Yxx, FMA2(c01r, Xyy, (-c01i)*Yyy)));
                v2 nY = FMA2(c00r, Yxx, FMA2( c00i, Xxx, FMA2(c01r, Yyy, ( c01i)*Xyy)));
                X[j] = nX; Y[j] = nY;
            }
        }
        LOADU(6);                                   // q6 -> k0: reg pairs (0,1),(2,3)
        gateCross(A, Bq, X[0], Y[0], X[1], Y[1]);
        gateCross(A, Bq, X[2], Y[2], X[3], Y[3]);
        #undef LOADU

        // --- CNOT ring CNOT(q, q+1 mod 7), reference order q=0..6 ---
        // (0,1)+(1,2)+(2,3) merged: new[u] = old[u ^ (u>>1)] — one gather
        #pragma unroll
        for (int j = 0; j < 4; ++j) {
            X[j].x = __shfl(X[j].x, srcLane); X[j].y = __shfl(X[j].y, srcLane);
            Y[j].x = __shfl(Y[j].x, srcLane); Y[j].y = __shfl(Y[j].y, srcLane);
        }
        {   // (3,4): ctrl u0 (lane&1), tgt k2 -> cond swap regs (0<->2),(1<->3)
            const bool cc = (lane & 1) != 0;
            v2 t;
            t = X[0]; X[0] = sel(cc, X[2], X[0]); X[2] = sel(cc, t, X[2]);
            t = X[1]; X[1] = sel(cc, X[3], X[1]); X[3] = sel(cc, t, X[3]);
            t = Y[0]; Y[0] = sel(cc, Y[2], Y[0]); Y[2] = sel(cc, t, Y[2]);
            t = Y[1]; Y[1] = sel(cc, Y[3], Y[1]); Y[3] = sel(cc, t, Y[3]);
        }
        {   // (4,5): ctrl k2 (regs 2,3), tgt k1 -> component swap
            X[2] = X[2].yx; X[3] = X[3].yx; Y[2] = Y[2].yx; Y[3] = Y[3].yx;
        }
        {   // (5,6): ctrl k1 (.y comps), tgt k0 -> swap .y across reg-bit0 pairs
            float t;
            t = X[0].y; X[0].y = X[1].y; X[1].y = t;
            t = X[2].y; X[2].y = X[3].y; X[3].y = t;
            t = Y[0].y; Y[0].y = Y[1].y; Y[1].y = t;
            t = Y[2].y; Y[2].y = Y[3].y; Y[3].y = t;
        }
        {   // (6,0): ctrl k0 (regs 1,3), tgt u3 -> xor8 whole regs (DPP)
            X[1] = shufv<8>(X[1]); X[3] = shufv<8>(X[3]);
            Y[1] = shufv<8>(Y[1]); Y[3] = shufv<8>(Y[3]);
        }
    }

    // ---------- <Z_j> ----------
    v2 P[4];
    #pragma unroll
    for (int j = 0; j < 4; ++j) P[j] = FMA2(X[j], X[j], Y[j]*Y[j]);
    const v2 Sa = P[0] + P[1], Sb = P[2] + P[3];   // k2 = 0 / 1
    const v2 Se = P[0] + P[2], So = P[1] + P[3];   // k0 = 0 / 1
    const v2 T  = Sa + Sb;
    const float t = T.x + T.y;
    float z[NQ];
    z[0] = (lane & 8) ? -t : t;
    z[1] = (lane & 4) ? -t : t;
    z[2] = (lane & 2) ? -t : t;
    z[3] = (lane & 1) ? -t : t;
    z[4] = (Sa.x + Sa.y) - (Sb.x + Sb.y);   // sign by k2
    z[5] = T.x - T.y;                       // sign by k1 (component)
    z[6] = (Se.x + Se.y) - (So.x + So.y);   // sign by k0
    // 16-lane reduction (R12-proven): xor1, xor2, then ror4/8/12 direction-immune
    #pragma unroll
    for (int j = 0; j < NQ; ++j) {
        float v = z[j];
        v += xorl<1>(v);
        v += xorl<2>(v);
        const float q4  = fdpp<0x124>(v);
        const float q8  = fdpp<0x128>(v);
        const float q12 = fdpp<0x12C>(v);
        z[j] = (v + q8) + (q4 + q12);
    }

    // ---------- MLP 7 -> 32(relu) -> 22, per 16-lane group (2 rows/lane) ----------
    float acc1a = fc1_b[u], acc1b = fc1_b[u + 16];
    #pragma unroll
    for (int j = 0; j < NQ; ++j) {
        acc1a = fmaf(z[j], fc1_w[u*NQ + j], acc1a);
        acc1b = fmaf(z[j], fc1_w[(u+16)*NQ + j], acc1b);
    }
    hbuf[grp][u]      = fmaxf(acc1a, 0.f);
    hbuf[grp][u + 16] = fmaxf(acc1b, 0.f);
    __builtin_amdgcn_wave_barrier();
    asm volatile("s_waitcnt lgkmcnt(0)" ::: "memory");
    __builtin_amdgcn_sched_barrier(0);

    float hv[32];
    #pragma unroll
    for (int i = 0; i < 8; ++i) {   // broadcast reads within each group
        float4 v4 = *reinterpret_cast<const float4*>(&hbuf[grp][i*4]);
        hv[i*4+0] = v4.x; hv[i*4+1] = v4.y; hv[i*4+2] = v4.z; hv[i*4+3] = v4.w;
    }
    const int kb = (u < NCLS - 16) ? (u + 16) : 0;   // clamp row for u>=6
    float acc2a = fc2_b[u], acc2b = fc2_b[kb];
    const float4* w4a = reinterpret_cast<const float4*>(fc2_w + u*32);
    const float4* w4b = reinterpret_cast<const float4*>(fc2_w + kb*32);
    #pragma unroll
    for (int i = 0; i < 8; ++i) {
        float4 wa = w4a[i], wb = w4b[i];
        acc2a = fmaf(hv[i*4+0], wa.x, acc2a); acc2b = fmaf(hv[i*4+0], wb.x, acc2b);
        acc2a = fmaf(hv[i*4+1], wa.y, acc2a); acc2b = fmaf(hv[i*4+1], wb.y, acc2b);
        acc2a = fmaf(hv[i*4+2], wa.z, acc2a); acc2b = fmaf(hv[i*4+2], wb.z, acc2b);
        acc2a = fmaf(hv[i*4+3], wa.w, acc2a); acc2b = fmaf(hv[i*4+3], wb.w, acc2b);
    }
    out[b*NCLS + u] = acc2a;
    if (u < NCLS - 16) out[b*NCLS + 16 + u] = acc2b;
}

extern "C" void kernel_launch(void* const* d_in, const int* in_sizes, int n_in,
                              void* d_out, int out_size, void* d_ws, size_t ws_size,
                              hipStream_t stream) {
    const float* x     = (const float*)d_in[0];
    const float* wts   = (const float*)d_in[1];
    const float* fc1_w = (const float*)d_in[2];
    const float* fc1_b = (const float*)d_in[3];
    const float* fc2_w = (const float*)d_in[4];
    const float* fc2_b = (const float*)d_in[5];
    float* out = (float*)d_out;

    const int B = in_sizes[0] / NQ;            // 16384
    const int grid = (B + EPB - 1) / EPB;      // 1024 blocks
    reupload_kernel<<<grid, 256, 0, stream>>>(x, wts, fc1_w, fc1_b, fc2_w, fc2_b, out, B);
}